// Round 14
// baseline (334.942 us; speedup 1.0000x reference)
//
#include <hip/hip_runtime.h>
#include <hip/hip_bf16.h>

typedef __attribute__((ext_vector_type(8))) short   bf16x8;
typedef __attribute__((ext_vector_type(4))) short   bf16x4;
typedef __attribute__((ext_vector_type(4))) float   f32x4;
typedef unsigned short u16;

#define NTOK 64
#define CEMB 192
#define NH   6
#define ROWB 384   // row bytes for [64][192] bf16 tiles
#define VROWB 128  // row bytes for vhT [192][64] bf16

__device__ __forceinline__ u16 f2b(float f) {
  unsigned u = __float_as_uint(f);
  unsigned r = (u + 0x7fffu + ((u >> 16) & 1u)) >> 16;  // RNE
  return (u16)r;
}

__device__ __forceinline__ unsigned cvtpk(float lo, float hi) {
  unsigned r;
  asm("v_cvt_pk_bf16_f32 %0, %1, %2" : "=v"(r) : "v"(lo), "v"(hi));
  return r;
}

__device__ __forceinline__ int swz(int row, int colbyte) {
  return colbyte ^ ((((row >> 3) ^ row) & 7) << 4);
}

__device__ __forceinline__ f32x4 mfma16(bf16x4 a, bf16x4 b, f32x4 c) {
  return __builtin_amdgcn_mfma_f32_16x16x16bf16_1k(a, b, c, 0, 0, 0);
}

union PK2 { unsigned u[2]; bf16x4 v; };

// ---------------- prep: pack W^T (bf16) + gather rel_bias ----------------
__global__ void prep_kernel(const float* __restrict__ Wq, const float* __restrict__ Wk,
                            const float* __restrict__ Wv, const float* __restrict__ Wp,
                            const float* __restrict__ btab, const int* __restrict__ ridx,
                            u16* __restrict__ WT, float* __restrict__ rb) {
  int idx = blockIdx.x * 256 + threadIdx.x;
  if (idx < 4 * 36864) {
    int m = idx / 36864;
    int e = idx - m * 36864;
    int n = e / CEMB;
    int k = e - n * CEMB;
    const float* W = (m == 0) ? Wq : (m == 1) ? Wk : (m == 2) ? Wv : Wp;
    WT[idx] = f2b(W[k * CEMB + n]);          // WT[m][n][k] = W[k][n]
  } else {
    int i2 = idx - 4 * 36864;
    if (i2 < NH * 4096) {
      int h = i2 >> 12;
      int ij = i2 & 4095;
      rb[i2] = btab[ridx[ij] * NH + h];      // rb[h][i][j]
    }
  }
}

// one attention unit (head h): S -> softmax -> prob store -> PV (R12-verified algebra).
// xa[ctv][r] = X[q = rt*16 + lhi*4 + r][chan = h*32 + ctv*16 + l15]
__device__ __forceinline__ void attn_unit(int h, bf16x4 qb0, bf16x4 qb1,
                                          const char* bKH, const char* bVT,
                                          const float* __restrict__ rb,
                                          const f32x4* mk4,
                                          float* __restrict__ ap_base,
                                          int qrow, int l15, int lhi,
                                          f32x4* xa) {
  // S quarters (K=16): lg4[ct][r] = S[q=qrow][k = ct*16 + lhi*4 + r]
  f32x4 lg4[4];
  #pragma unroll
  for (int ct = 0; ct < 4; ++ct) {
    int krow = ct * 16 + l15;
    bf16x4 a0 = *reinterpret_cast<const bf16x4*>(bKH + krow * ROWB + swz(krow, h * 64 + lhi * 8));
    bf16x4 a1 = *reinterpret_cast<const bf16x4*>(bKH + krow * ROWB + swz(krow, h * 64 + 32 + lhi * 8));
    f32x4 z = {0.f, 0.f, 0.f, 0.f};
    f32x4 s = mfma16(a0, qb0, z);
    s = mfma16(a1, qb1, s);
    f32x4 r4 = *reinterpret_cast<const f32x4*>(rb + h * 4096 + qrow * 64 + ct * 16 + lhi * 4);
    #pragma unroll
    for (int r = 0; r < 4; ++r) lg4[ct][r] = s[r] + r4[r] + mk4[ct][r];
  }

  float mx = fmaxf(fmaxf(fmaxf(lg4[0][0], lg4[0][1]), fmaxf(lg4[0][2], lg4[0][3])),
                   fmaxf(fmaxf(lg4[1][0], lg4[1][1]), fmaxf(lg4[1][2], lg4[1][3])));
  mx = fmaxf(mx, fmaxf(fmaxf(fmaxf(lg4[2][0], lg4[2][1]), fmaxf(lg4[2][2], lg4[2][3])),
                       fmaxf(fmaxf(lg4[3][0], lg4[3][1]), fmaxf(lg4[3][2], lg4[3][3]))));
  mx = fmaxf(mx, __shfl_xor(mx, 16));
  mx = fmaxf(mx, __shfl_xor(mx, 32));

  float sum = 0.f;
  #pragma unroll
  for (int ct = 0; ct < 4; ++ct)
    #pragma unroll
    for (int r = 0; r < 4; ++r) {
      lg4[ct][r] = __expf(lg4[ct][r] - mx);
      sum += lg4[ct][r];
    }
  sum += __shfl_xor(sum, 16);
  sum += __shfl_xor(sum, 32);
  float inv = 1.0f / sum;

  float* ap = ap_base + (size_t)h * 4096 + qrow * 64;
  PK2 pa[4];
  #pragma unroll
  for (int ct = 0; ct < 4; ++ct) {
    f32x4 p4;
    #pragma unroll
    for (int r = 0; r < 4; ++r) p4[r] = lg4[ct][r] * inv;
    *reinterpret_cast<f32x4*>(ap + ct * 16 + lhi * 4) = p4;
    pa[ct].u[0] = cvtpk(p4[0], p4[1]);
    pa[ct].u[1] = cvtpk(p4[2], p4[3]);
  }

  // PV (R12 order): xa[ctv] = sum_ct mfma16(P-frag, V-frag)
  { f32x4 z = {0.f, 0.f, 0.f, 0.f}; xa[0] = z; xa[1] = z; }
  #pragma unroll
  for (int ctv = 0; ctv < 2; ++ctv) {
    int vrow = h * 32 + ctv * 16 + l15;
    #pragma unroll
    for (int ct = 0; ct < 4; ++ct) {
      bf16x4 bvf = *reinterpret_cast<const bf16x4*>(bVT + vrow * VROWB + swz(vrow, ct * 32 + lhi * 8));
      xa[ctv] = mfma16(pa[ct].v, bvf, xa[ctv]);
    }
  }
}

// ---------------- fused window attention: 256 thr, 48KB LDS, 3 blocks/CU ----------------
__global__ __launch_bounds__(256, 3)
void wattn_kernel(const float* __restrict__ qg, const float* __restrict__ kg,
                  const float* __restrict__ vg, const float* __restrict__ maskg,
                  const float* __restrict__ bq, const float* __restrict__ bk,
                  const float* __restrict__ bv, const float* __restrict__ bp,
                  const u16* __restrict__ WT, const float* __restrict__ rb,
                  float* __restrict__ xout, float* __restrict__ attn_out) {
  __shared__ __align__(16) char smem[49152];
  char* bA = smem;            // raw q -> raw v -> vhT [192][64]
  char* bB = smem + 24576;    // raw k -> kh [64][192] -> X alias
  const int tid  = threadIdx.x;
  const int wave = tid >> 6;           // 0..3 == rt
  const int lane = tid & 63;
  const int l15  = lane & 15;
  const int lhi  = lane >> 4;
  const int b    = blockIdx.x;
  const int rt   = wave;
  const int qrow = rt * 16 + l15;
  const float scale = 0.17677669529663687f;

  const size_t base = (size_t)b * NTOK * CEMB;

  // ---- Phase 1a: stage raw q -> bA, raw k -> bB ----
  #pragma unroll
  for (int it = 0; it < 12; ++it) {
    int fi  = it * 256 + tid;
    int row = fi / 48;
    int ce  = (fi - row * 48) * 4;
    float4 v4 = reinterpret_cast<const float4*>(qg + base)[fi];
    uint2 w;
    w.x = cvtpk(v4.x, v4.y); w.y = cvtpk(v4.z, v4.w);
    *reinterpret_cast<uint2*>(bA + row * ROWB + swz(row, ce * 2)) = w;
    float4 v5 = reinterpret_cast<const float4*>(kg + base)[fi];
    uint2 w2;
    w2.x = cvtpk(v5.x, v5.y); w2.y = cvtpk(v5.z, v5.w);
    *reinterpret_cast<uint2*>(bB + row * ROWB + swz(row, ce * 2)) = w2;
  }
  __syncthreads();   // S1

  // ---- Phase 2a: q-pass -> qb[12] regs (verified mfma(W,x) form, all strips) ----
  bf16x4 qb[12];
  #pragma unroll
  for (int c = 0; c < 2; ++c) {
    f32x4 qa[6];
    #pragma unroll
    for (int j = 0; j < 6; ++j) { f32x4 z = {0.f,0.f,0.f,0.f}; qa[j] = z; }
    #pragma unroll
    for (int ks = 0; ks < 6; ++ks) {
      bf16x8 ax = *reinterpret_cast<const bf16x8*>(bA + qrow * ROWB + swz(qrow, ks * 64 + lhi * 16));
      #pragma unroll
      for (int j = 0; j < 6; ++j) {
        int strip = c * 6 + j;
        bf16x8 bw = *reinterpret_cast<const bf16x8*>(WT + (strip * 16 + l15) * CEMB + ks * 32 + lhi * 8);
        qa[j] = __builtin_amdgcn_mfma_f32_16x16x32_bf16(bw, ax, qa[j], 0, 0, 0);
      }
    }
    #pragma unroll
    for (int j = 0; j < 6; ++j) {
      int strip = c * 6 + j;
      f32x4 b4 = *reinterpret_cast<const f32x4*>(bq + strip * 16 + lhi * 4);
      PK2 pk;
      pk.u[0] = cvtpk((qa[j][0] + b4[0]) * scale, (qa[j][1] + b4[1]) * scale);
      pk.u[1] = cvtpk((qa[j][2] + b4[2]) * scale, (qa[j][3] + b4[3]) * scale);
      qb[strip] = pk.v;
    }
  }
  __syncthreads();   // S2: raw-q reads of bA done

  // ---- Phase 1b: stage raw v -> bA ----
  #pragma unroll
  for (int it = 0; it < 12; ++it) {
    int fi  = it * 256 + tid;
    int row = fi / 48;
    int ce  = (fi - row * 48) * 4;
    float4 v4 = reinterpret_cast<const float4*>(vg + base)[fi];
    uint2 w;
    w.x = cvtpk(v4.x, v4.y); w.y = cvtpk(v4.z, v4.w);
    *reinterpret_cast<uint2*>(bA + row * ROWB + swz(row, ce * 2)) = w;
  }
  // no barrier: next phase reads bB only; S3 fences these writes

  // ---- Phase 2b: k-pass (R12 form: mfma(x, W)), kh -> bB in place ----
  {
    f32x4 acc[3][4];
    #pragma unroll
    for (int si = 0; si < 3; ++si) {
      int strip = wave + si * 4;
      const u16* Wt = WT + 36864 + (strip * 16 + l15) * CEMB + lhi * 8;
      #pragma unroll
      for (int r2 = 0; r2 < 4; ++r2) { f32x4 z = {0.f,0.f,0.f,0.f}; acc[si][r2] = z; }
      #pragma unroll
      for (int ks = 0; ks < 6; ++ks) {
        bf16x8 bw = *reinterpret_cast<const bf16x8*>(Wt + ks * 32);
        #pragma unroll
        for (int r2 = 0; r2 < 4; ++r2) {
          int row = r2 * 16 + l15;
          bf16x8 ax = *reinterpret_cast<const bf16x8*>(bB + row * ROWB + swz(row, ks * 64 + lhi * 16));
          acc[si][r2] = __builtin_amdgcn_mfma_f32_16x16x32_bf16(ax, bw, acc[si][r2], 0, 0, 0);
        }
      }
    }
    __syncthreads();   // S3: raw-k reads done AND 1b v-writes visible
    #pragma unroll
    for (int si = 0; si < 3; ++si) {
      int strip = wave + si * 4;
      int c = strip * 16 + l15;
      float bval = bk[c];
      #pragma unroll
      for (int r2 = 0; r2 < 4; ++r2)
        #pragma unroll
        for (int r = 0; r < 4; ++r) {
          int row = r2 * 16 + lhi * 4 + r;
          *reinterpret_cast<u16*>(bB + row * ROWB + swz(row, c * 2)) = f2b(acc[si][r2][r] + bval);
        }
    }
  }

  // ---- Phase 2c: v-pass (R12 form), vhT -> bA in place ----
  {
    f32x4 acc[3][4];
    #pragma unroll
    for (int si = 0; si < 3; ++si) {
      int strip = wave + si * 4;
      const u16* Wt = WT + 2 * 36864 + (strip * 16 + l15) * CEMB + lhi * 8;
      #pragma unroll
      for (int r2 = 0; r2 < 4; ++r2) { f32x4 z = {0.f,0.f,0.f,0.f}; acc[si][r2] = z; }
      #pragma unroll
      for (int ks = 0; ks < 6; ++ks) {
        bf16x8 bw = *reinterpret_cast<const bf16x8*>(Wt + ks * 32);
        #pragma unroll
        for (int r2 = 0; r2 < 4; ++r2) {
          int row = r2 * 16 + l15;
          bf16x8 ax = *reinterpret_cast<const bf16x8*>(bA + row * ROWB + swz(row, ks * 64 + lhi * 16));
          acc[si][r2] = __builtin_amdgcn_mfma_f32_16x16x32_bf16(ax, bw, acc[si][r2], 0, 0, 0);
        }
      }
    }
    __syncthreads();   // S4: raw-v reads done
    #pragma unroll
    for (int si = 0; si < 3; ++si) {
      int strip = wave + si * 4;
      int c = strip * 16 + l15;
      float bval = bv[c];
      #pragma unroll
      for (int r2 = 0; r2 < 4; ++r2) {
        int t0 = r2 * 16 + lhi * 4;
        uint2 w;
        w.x = cvtpk(acc[si][r2][0] + bval, acc[si][r2][1] + bval);
        w.y = cvtpk(acc[si][r2][2] + bval, acc[si][r2][3] + bval);
        *reinterpret_cast<uint2*>(bA + c * VROWB + swz(c, t0 * 2)) = w;
      }
    }
  }
  __syncthreads();   // S5: kh + vhT ready

  // ---- Phase 3: head pairs; X (regs) -> retired kh cols after pair barrier ----
  const float* maskw = maskg + (size_t)(b & 1023) * 4096;
  f32x4 mk4[4];
  #pragma unroll
  for (int ct = 0; ct < 4; ++ct)
    mk4[ct] = *reinterpret_cast<const f32x4*>(maskw + qrow * 64 + ct * 16 + lhi * 4);
  float* ap_base = attn_out + (size_t)b * NH * 4096;

  #pragma unroll
  for (int ri = 0; ri < 3; ++ri) {
    f32x4 xaA[2], xaB[2];
    attn_unit(2 * ri,     qb[4 * ri],     qb[4 * ri + 1], bB, bA, rb, mk4, ap_base, qrow, l15, lhi, xaA);
    attn_unit(2 * ri + 1, qb[4 * ri + 2], qb[4 * ri + 3], bB, bA, rb, mk4, ap_base, qrow, l15, lhi, xaB);
    __syncthreads();   // all kh reads of this 128B head-pair range done

    // X scalar stores (R12 mapping): rows rt*16+lhi*4+r, col h*32+ctv*16+l15
    #pragma unroll
    for (int ctv = 0; ctv < 2; ++ctv)
      #pragma unroll
      for (int r = 0; r < 4; ++r) {
        int xrow = rt * 16 + lhi * 4 + r;
        int xcA = (2 * ri) * 32 + ctv * 16 + l15;
        int xcB = (2 * ri + 1) * 32 + ctv * 16 + l15;
        *reinterpret_cast<u16*>(bB + xrow * ROWB + swz(xrow, xcA * 2)) = f2b(xaA[ctv][r]);
        *reinterpret_cast<u16*>(bB + xrow * ROWB + swz(xrow, xcB * 2)) = f2b(xaB[ctv][r]);
      }
  }
  __syncthreads();   // X complete

  // ---- Phase 4: out = X @ Wp + bp (R12 form), 24 units over 4 waves ----
  #pragma unroll
  for (int ui = 0; ui < 6; ++ui) {
    int u2 = wave + ui * 4;            // 0..23
    int ct = u2 % 12;
    int rh = u2 / 12;
    const u16* Wt = WT + 3 * 36864 + (ct * 16 + l15) * CEMB + lhi * 8;
    f32x4 oa[2];
    { f32x4 z = {0.f, 0.f, 0.f, 0.f}; oa[0] = z; oa[1] = z; }
    #pragma unroll
    for (int ks = 0; ks < 6; ++ks) {
      bf16x8 bw = *reinterpret_cast<const bf16x8*>(Wt + ks * 32);
      #pragma unroll
      for (int rr = 0; rr < 2; ++rr) {
        int xrow = rh * 32 + rr * 16 + l15;
        bf16x8 ax = *reinterpret_cast<const bf16x8*>(bB + xrow * ROWB + swz(xrow, ks * 64 + lhi * 16));
        oa[rr] = __builtin_amdgcn_mfma_f32_16x16x32_bf16(ax, bw, oa[rr], 0, 0, 0);
      }
    }
    float bias = bp[ct * 16 + l15];
    #pragma unroll
    for (int rr = 0; rr < 2; ++rr)
      #pragma unroll
      for (int r = 0; r < 4; ++r)
        xout[((size_t)b * NTOK + rh * 32 + rr * 16 + lhi * 4 + r) * CEMB + ct * 16 + l15] = oa[rr][r] + bias;
  }
}

extern "C" void kernel_launch(void* const* d_in, const int* in_sizes, int n_in,
                              void* d_out, int out_size, void* d_ws, size_t ws_size,
                              hipStream_t stream) {
  const float* q    = (const float*)d_in[0];
  const float* k    = (const float*)d_in[1];
  const float* v    = (const float*)d_in[2];
  const float* mask = (const float*)d_in[3];
  const float* Wq   = (const float*)d_in[4];
  const float* bq   = (const float*)d_in[5];
  const float* Wk   = (const float*)d_in[6];
  const float* bk   = (const float*)d_in[7];
  const float* Wv   = (const float*)d_in[8];
  const float* bv   = (const float*)d_in[9];
  const float* Wp   = (const float*)d_in[10];
  const float* bp   = (const float*)d_in[11];
  const float* btab = (const float*)d_in[12];
  const int*   ridx = (const int*)d_in[13];

  u16*   WT = (u16*)d_ws;                               // 4 * 36864 bf16
  float* rb = (float*)((char*)d_ws + 4 * 36864 * 2);    // 6*64*64 fp32

  float* xout = (float*)d_out;
  float* attn = xout + (size_t)2048 * NTOK * CEMB;

  prep_kernel<<<672, 256, 0, stream>>>(Wq, Wk, Wv, Wp, btab, ridx, WT, rb);
  wattn_kernel<<<2048, 256, 0, stream>>>(q, k, v, mask, bq, bk, bv, bp, WT, rb, xout, attn);
}

// Round 16
// 250.868 us; speedup vs baseline: 1.3351x; 1.3351x over previous
//
#include <hip/hip_runtime.h>
#include <hip/hip_bf16.h>

typedef __attribute__((ext_vector_type(8))) short   bf16x8;
typedef __attribute__((ext_vector_type(4))) short   bf16x4;
typedef __attribute__((ext_vector_type(4))) float   f32x4;
typedef unsigned short u16;

#define NTOK 64
#define CEMB 192
#define NH   6
#define ROWB 384   // row bytes for [64][192] bf16 tiles
#define VROWB 128  // row bytes for vhT [192][64] bf16

__device__ __forceinline__ u16 f2b(float f) {
  unsigned u = __float_as_uint(f);
  unsigned r = (u + 0x7fffu + ((u >> 16) & 1u)) >> 16;  // RNE
  return (u16)r;
}

__device__ __forceinline__ unsigned cvtpk(float lo, float hi) {
  unsigned r;
  asm("v_cvt_pk_bf16_f32 %0, %1, %2" : "=v"(r) : "v"(lo), "v"(hi));
  return r;
}

__device__ __forceinline__ int swz(int row, int colbyte) {
  return colbyte ^ ((((row >> 3) ^ row) & 7) << 4);
}

__device__ __forceinline__ f32x4 mfma16(bf16x4 a, bf16x4 b, f32x4 c) {
  return __builtin_amdgcn_mfma_f32_16x16x16bf16_1k(a, b, c, 0, 0, 0);
}

union PK2 { unsigned u[2]; bf16x4 v; };

// ---------------- prep: pack W^T (bf16) + gather rel_bias ----------------
__global__ void prep_kernel(const float* __restrict__ Wq, const float* __restrict__ Wk,
                            const float* __restrict__ Wv, const float* __restrict__ Wp,
                            const float* __restrict__ btab, const int* __restrict__ ridx,
                            u16* __restrict__ WT, float* __restrict__ rb) {
  int idx = blockIdx.x * 256 + threadIdx.x;
  if (idx < 4 * 36864) {
    int m = idx / 36864;
    int e = idx - m * 36864;
    int n = e / CEMB;
    int k = e - n * CEMB;
    const float* W = (m == 0) ? Wq : (m == 1) ? Wk : (m == 2) ? Wv : Wp;
    WT[idx] = f2b(W[k * CEMB + n]);          // WT[m][n][k] = W[k][n]
  } else {
    int i2 = idx - 4 * 36864;
    if (i2 < NH * 4096) {
      int h = i2 >> 12;
      int ij = i2 & 4095;
      rb[i2] = btab[ridx[ij] * NH + h];      // rb[h][i][j]
    }
  }
}

// ---------------- fused window attention, 48KB LDS (R12 structure, (512,4) bound) ----------------
__global__ __launch_bounds__(512, 4)
void wattn_kernel(const float* __restrict__ qg, const float* __restrict__ kg,
                  const float* __restrict__ vg, const float* __restrict__ maskg,
                  const float* __restrict__ bq, const float* __restrict__ bk,
                  const float* __restrict__ bv, const float* __restrict__ bp,
                  const u16* __restrict__ WT, const float* __restrict__ rb,
                  float* __restrict__ xout, float* __restrict__ attn_out) {
  __shared__ __align__(16) char smem[49152];
  char* bA = smem;            // raw q -> raw v -> vhT [192][64]
  char* bB = smem + 24576;    // raw k -> kh [64][192] -> X alias
  const int tid  = threadIdx.x;
  const int wave = tid >> 6;
  const int lane = tid & 63;
  const int l15  = lane & 15;
  const int lhi  = lane >> 4;
  const int b    = blockIdx.x;
  const int rt   = wave & 3;           // row-tile owned by this wave
  const int p    = wave >> 2;          // head parity
  const float scale = 0.17677669529663687f;

  const size_t base = (size_t)b * NTOK * CEMB;

  // ---- Phase 1a: stage raw q -> bA, raw k -> bB ----
  #pragma unroll
  for (int it = 0; it < 6; ++it) {
    int fi  = it * 512 + tid;
    int row = fi / 48;
    int ce  = (fi - row * 48) * 4;
    float4 v4 = reinterpret_cast<const float4*>(qg + base)[fi];
    uint2 w;
    w.x = cvtpk(v4.x, v4.y); w.y = cvtpk(v4.z, v4.w);
    *reinterpret_cast<uint2*>(bA + row * ROWB + swz(row, ce * 2)) = w;
    float4 v5 = reinterpret_cast<const float4*>(kg + base)[fi];
    uint2 w2;
    w2.x = cvtpk(v5.x, v5.y); w2.y = cvtpk(v5.z, v5.w);
    *reinterpret_cast<uint2*>(bB + row * ROWB + swz(row, ce * 2)) = w2;
  }
  __syncthreads();   // S1

  // ---- Phase 2a: q-pass -> qb registers. Wave computes qh for ITS 3 heads
  //      (h = p, p+2, p+4), own rt rows; mfma(W, x) -> D[chan][token] ----
  bf16x4 qb[6];
  {
    f32x4 qa[6];
    #pragma unroll
    for (int s6 = 0; s6 < 6; ++s6) { f32x4 z = {0.f,0.f,0.f,0.f}; qa[s6] = z; }
    int row = rt * 16 + l15;
    #pragma unroll
    for (int ks = 0; ks < 6; ++ks) {
      bf16x8 ax = *reinterpret_cast<const bf16x8*>(bA + row * ROWB + swz(row, ks * 64 + lhi * 16));
      #pragma unroll
      for (int s6 = 0; s6 < 6; ++s6) {
        int strip = (p + (s6 >> 1) * 2) * 2 + (s6 & 1);
        bf16x8 bw = *reinterpret_cast<const bf16x8*>(WT + (strip * 16 + l15) * CEMB + ks * 32 + lhi * 8);
        qa[s6] = __builtin_amdgcn_mfma_f32_16x16x32_bf16(bw, ax, qa[s6], 0, 0, 0);
      }
    }
    #pragma unroll
    for (int s6 = 0; s6 < 6; ++s6) {
      int strip = (p + (s6 >> 1) * 2) * 2 + (s6 & 1);
      f32x4 b4 = *reinterpret_cast<const f32x4*>(bq + strip * 16 + lhi * 4);
      PK2 pk;
      pk.u[0] = cvtpk((qa[s6][0] + b4[0]) * scale, (qa[s6][1] + b4[1]) * scale);
      pk.u[1] = cvtpk((qa[s6][2] + b4[2]) * scale, (qa[s6][3] + b4[3]) * scale);
      qb[s6] = pk.v;
    }
  }
  __syncthreads();   // S2: raw-q reads of bA done

  // ---- Phase 1b: stage raw v -> bA (first and only v read) ----
  #pragma unroll
  for (int it = 0; it < 6; ++it) {
    int fi  = it * 512 + tid;
    int row = fi / 48;
    int ce  = (fi - row * 48) * 4;
    float4 v4 = reinterpret_cast<const float4*>(vg + base)[fi];
    uint2 w;
    w.x = cvtpk(v4.x, v4.y); w.y = cvtpk(v4.z, v4.w);
    *reinterpret_cast<uint2*>(bA + row * ROWB + swz(row, ce * 2)) = w;
  }
  // no barrier: next phase reads bB only; S3 below fences these writes

  // ---- Phase 2b: k-pass (reads bB), kh -> bB in place ----
  {
    f32x4 acc[2][4];
    #pragma unroll
    for (int si = 0; si < 2; ++si) {
      int strip = wave + si * 8;
      if (strip < 12) {
        const u16* Wt = WT + 36864 + (strip * 16 + l15) * CEMB + lhi * 8;
        #pragma unroll
        for (int r2 = 0; r2 < 4; ++r2) { f32x4 z = {0.f,0.f,0.f,0.f}; acc[si][r2] = z; }
        #pragma unroll
        for (int ks = 0; ks < 6; ++ks) {
          bf16x8 bw = *reinterpret_cast<const bf16x8*>(Wt + ks * 32);
          #pragma unroll
          for (int r2 = 0; r2 < 4; ++r2) {
            int row = r2 * 16 + l15;
            bf16x8 ax = *reinterpret_cast<const bf16x8*>(bB + row * ROWB + swz(row, ks * 64 + lhi * 16));
            acc[si][r2] = __builtin_amdgcn_mfma_f32_16x16x32_bf16(ax, bw, acc[si][r2], 0, 0, 0);
          }
        }
      }
    }
    __syncthreads();   // S3: raw-k reads done AND 1b v-writes visible
    #pragma unroll
    for (int si = 0; si < 2; ++si) {
      int strip = wave + si * 8;
      if (strip < 12) {
        int c = strip * 16 + l15;
        float bval = bk[c];
        #pragma unroll
        for (int r2 = 0; r2 < 4; ++r2)
          #pragma unroll
          for (int r = 0; r < 4; ++r) {
            int row = r2 * 16 + lhi * 4 + r;
            *reinterpret_cast<u16*>(bB + row * ROWB + swz(row, c * 2)) = f2b(acc[si][r2][r] + bval);
          }
      }
    }
  }

  // ---- Phase 2c: v-pass (reads bA), vhT -> bA in place ----
  {
    f32x4 acc[2][4];
    #pragma unroll
    for (int si = 0; si < 2; ++si) {
      int strip = wave + si * 8;
      if (strip < 12) {
        const u16* Wt = WT + 2 * 36864 + (strip * 16 + l15) * CEMB + lhi * 8;
        #pragma unroll
        for (int r2 = 0; r2 < 4; ++r2) { f32x4 z = {0.f,0.f,0.f,0.f}; acc[si][r2] = z; }
        #pragma unroll
        for (int ks = 0; ks < 6; ++ks) {
          bf16x8 bw = *reinterpret_cast<const bf16x8*>(Wt + ks * 32);
          #pragma unroll
          for (int r2 = 0; r2 < 4; ++r2) {
            int row = r2 * 16 + l15;
            bf16x8 ax = *reinterpret_cast<const bf16x8*>(bA + row * ROWB + swz(row, ks * 64 + lhi * 16));
            acc[si][r2] = __builtin_amdgcn_mfma_f32_16x16x32_bf16(ax, bw, acc[si][r2], 0, 0, 0);
          }
        }
      }
    }
    __syncthreads();   // S4: raw-v reads done (kh epilogue writes also before this)
    #pragma unroll
    for (int si = 0; si < 2; ++si) {
      int strip = wave + si * 8;
      if (strip < 12) {
        int c = strip * 16 + l15;
        float bval = bv[c];
        #pragma unroll
        for (int r2 = 0; r2 < 4; ++r2) {
          int t0 = r2 * 16 + lhi * 4;
          uint2 w;
          w.x = cvtpk(acc[si][r2][0] + bval, acc[si][r2][1] + bval);
          w.y = cvtpk(acc[si][r2][2] + bval, acc[si][r2][3] + bval);
          *reinterpret_cast<uint2*>(bA + c * VROWB + swz(c, t0 * 2)) = w;
        }
      }
    }
  }
  __syncthreads();   // S5: kh + vhT ready

  // ---- Phase 3: rounds ui = 0..2, head h = 2*ui + p ----
  const float* maskw = maskg + (size_t)(b & 1023) * 4096;
  const int qrow = rt * 16 + l15;

  #pragma unroll
  for (int ui = 0; ui < 3; ++ui) {
    int h = 2 * ui + p;

    // S quarters (K=16): lg4[ct][r] = S[q=qrow][k = ct*16 + lhi*4 + r]
    f32x4 lg4[4];
    #pragma unroll
    for (int ct = 0; ct < 4; ++ct) {
      int krow = ct * 16 + l15;
      bf16x4 a0 = *reinterpret_cast<const bf16x4*>(bB + krow * ROWB + swz(krow, h * 64 + lhi * 8));
      bf16x4 a1 = *reinterpret_cast<const bf16x4*>(bB + krow * ROWB + swz(krow, h * 64 + 32 + lhi * 8));
      f32x4 z = {0.f, 0.f, 0.f, 0.f};
      f32x4 s = mfma16(a0, qb[2 * ui], z);
      s = mfma16(a1, qb[2 * ui + 1], s);
      f32x4 r4 = *reinterpret_cast<const f32x4*>(rb + h * 4096 + qrow * 64 + ct * 16 + lhi * 4);
      f32x4 m4 = *reinterpret_cast<const f32x4*>(maskw + qrow * 64 + ct * 16 + lhi * 4);
      #pragma unroll
      for (int r = 0; r < 4; ++r) lg4[ct][r] = s[r] + r4[r] + m4[r];
    }

    // in-register softmax over k (16 local + shfl 16, 32)
    float mx = fmaxf(fmaxf(fmaxf(lg4[0][0], lg4[0][1]), fmaxf(lg4[0][2], lg4[0][3])),
                     fmaxf(fmaxf(lg4[1][0], lg4[1][1]), fmaxf(lg4[1][2], lg4[1][3])));
    mx = fmaxf(mx, fmaxf(fmaxf(fmaxf(lg4[2][0], lg4[2][1]), fmaxf(lg4[2][2], lg4[2][3])),
                         fmaxf(fmaxf(lg4[3][0], lg4[3][1]), fmaxf(lg4[3][2], lg4[3][3]))));
    mx = fmaxf(mx, __shfl_xor(mx, 16));
    mx = fmaxf(mx, __shfl_xor(mx, 32));

    float sum = 0.f;
    #pragma unroll
    for (int ct = 0; ct < 4; ++ct)
      #pragma unroll
      for (int r = 0; r < 4; ++r) {
        lg4[ct][r] = __expf(lg4[ct][r] - mx);
        sum += lg4[ct][r];
      }
    sum += __shfl_xor(sum, 16);
    sum += __shfl_xor(sum, 32);
    float inv = 1.0f / sum;

    // prob stores (float4) + P -> bf16 A-frags (lane-local, no LDS bridge)
    float* ap = attn_out + ((size_t)b * NH + h) * 4096 + qrow * 64;
    PK2 pa[4];
    #pragma unroll
    for (int ct = 0; ct < 4; ++ct) {
      f32x4 p4;
      #pragma unroll
      for (int r = 0; r < 4; ++r) p4[r] = lg4[ct][r] * inv;
      *reinterpret_cast<f32x4*>(ap + ct * 16 + lhi * 4) = p4;
      pa[ct].u[0] = cvtpk(p4[0], p4[1]);
      pa[ct].u[1] = cvtpk(p4[2], p4[3]);
    }

    // PV quarters (K=16): xa[ctv][r] = X[q = rt*16+lhi*4+r][chan = h*32+ctv*16+l15]
    f32x4 xa[2];
    { f32x4 z = {0.f, 0.f, 0.f, 0.f}; xa[0] = z; xa[1] = z; }
    #pragma unroll
    for (int ctv = 0; ctv < 2; ++ctv) {
      int vrow = h * 32 + ctv * 16 + l15;
      #pragma unroll
      for (int ct = 0; ct < 4; ++ct) {
        bf16x4 bvf = *reinterpret_cast<const bf16x4*>(bA + vrow * VROWB + swz(vrow, ct * 32 + lhi * 8));
        xa[ctv] = mfma16(pa[ct].v, bvf, xa[ctv]);
      }
    }
    __syncthreads();   // all kh reads of this head-pair's columns done

    // X into retired kh columns of bB (head-pair 128B swz-closed range)
    #pragma unroll
    for (int ctv = 0; ctv < 2; ++ctv)
      #pragma unroll
      for (int r = 0; r < 4; ++r) {
        int xrow = rt * 16 + lhi * 4 + r;
        int xcol = h * 32 + ctv * 16 + l15;
        *reinterpret_cast<u16*>(bB + xrow * ROWB + swz(xrow, xcol * 2)) = f2b(xa[ctv][r]);
      }
  }
  __syncthreads();   // X complete

  // ---- Phase 4: out = X @ Wp + bp (X in bB) ----
  #pragma unroll
  for (int ui = 0; ui < 3; ++ui) {
    int u2 = wave + ui * 8;
    int ct = u2 % 12;
    int rh = u2 / 12;
    const u16* Wt = WT + 3 * 36864 + (ct * 16 + l15) * CEMB + lhi * 8;
    f32x4 oa[2];
    { f32x4 z = {0.f, 0.f, 0.f, 0.f}; oa[0] = z; oa[1] = z; }
    #pragma unroll
    for (int ks = 0; ks < 6; ++ks) {
      bf16x8 bw = *reinterpret_cast<const bf16x8*>(Wt + ks * 32);
      #pragma unroll
      for (int rr = 0; rr < 2; ++rr) {
        int xrow = rh * 32 + rr * 16 + l15;
        bf16x8 ax = *reinterpret_cast<const bf16x8*>(bB + xrow * ROWB + swz(xrow, ks * 64 + lhi * 16));
        oa[rr] = __builtin_amdgcn_mfma_f32_16x16x32_bf16(ax, bw, oa[rr], 0, 0, 0);
      }
    }
    float bias = bp[ct * 16 + l15];
    #pragma unroll
    for (int rr = 0; rr < 2; ++rr)
      #pragma unroll
      for (int r = 0; r < 4; ++r)
        xout[((size_t)b * NTOK + rh * 32 + rr * 16 + lhi * 4 + r) * CEMB + ct * 16 + l15] = oa[rr][r] + bias;
  }
}

extern "C" void kernel_launch(void* const* d_in, const int* in_sizes, int n_in,
                              void* d_out, int out_size, void* d_ws, size_t ws_size,
                              hipStream_t stream) {
  const float* q    = (const float*)d_in[0];
  const float* k    = (const float*)d_in[1];
  const float* v    = (const float*)d_in[2];
  const float* mask = (const float*)d_in[3];
  const float* Wq   = (const float*)d_in[4];
  const float* bq   = (const float*)d_in[5];
  const float* Wk   = (const float*)d_in[6];
  const float* bk   = (const float*)d_in[7];
  const float* Wv   = (const float*)d_in[8];
  const float* bv   = (const float*)d_in[9];
  const float* Wp   = (const float*)d_in[10];
  const float* bp   = (const float*)d_in[11];
  const float* btab = (const float*)d_in[12];
  const int*   ridx = (const int*)d_in[13];

  u16*   WT = (u16*)d_ws;                               // 4 * 36864 bf16
  float* rb = (float*)((char*)d_ws + 4 * 36864 * 2);    // 6*64*64 fp32

  float* xout = (float*)d_out;
  float* attn = xout + (size_t)2048 * NTOK * CEMB;

  prep_kernel<<<672, 256, 0, stream>>>(Wq, Wk, Wv, Wp, btab, ridx, WT, rb);
  wattn_kernel<<<2048, 512, 0, stream>>>(q, k, v, mask, bq, bk, bv, bp, WT, rb, xout, attn);
}